// Round 24
// baseline (887.578 us; speedup 1.0000x reference)
//
#include <hip/hip_runtime.h>

// ---------------------------------------------------------------------------
// UnpoolWithSkip — round 24: r23 state + T5 s_setprio(1) around the MFMA
// clusters in F2t (phase3/phase4) and S2h (phase2). r23's intra-wave barrier
// deletion created wave role-diversity (gather-issuing vs MFMA waves), which
// is T5's prerequisite. Pure scheduler hint; everything else identical.
// ---------------------------------------------------------------------------

typedef unsigned short u16;
typedef unsigned int   u32;
typedef __attribute__((ext_vector_type(4))) float f32x4;
typedef __attribute__((ext_vector_type(8))) short s16x8;
typedef __attribute__((ext_vector_type(4))) int   i32x4;

#define NN 16384
#define MM 65536
#define MKCNT 1048576
#define EPS 1e-5f

__device__ __forceinline__ float uf(u16 u){ union{u32 i; float f;} x; x.i = ((u32)u)<<16; return x.f; }
__device__ __forceinline__ u16 fu(float f){ u32 x = __float_as_uint(f); u32 r = (x + 0x7fffu + ((x>>16)&1u))>>16; return (u16)r; }

__global__ void k_fill(float* o, int nsz){
  int i = blockIdx.x*256 + threadIdx.x;
  if(i < nsz) o[i] = 12345.0f;
}

// ---------------- counting sort by cluster ----------------
__global__ __launch_bounds__(256) void k_count(const int* __restrict__ clu, int* __restrict__ cnt){
  int m = blockIdx.x*256 + threadIdx.x;
  atomicAdd(&cnt[clu[m]], 1);
}
__global__ __launch_bounds__(256) void k_scan(int* __restrict__ cnt, int* __restrict__ offs){
  __shared__ int part[256];
  int t = threadIdx.x;
  int s = 0;
  #pragma unroll 1
  for(int i=0;i<64;i++) s += cnt[t*64+i];
  part[t] = s;
  __syncthreads();
  if(t==0){ int run=0; for(int i=0;i<256;i++){ int tmp=part[i]; part[i]=run; run+=tmp; } }
  __syncthreads();
  int run = part[t];
  #pragma unroll 1
  for(int i=0;i<64;i++){ int c = cnt[t*64+i]; offs[t*64+i] = run; run += c; cnt[t*64+i] = 0; }
}
__global__ __launch_bounds__(256) void k_scatter(const int* __restrict__ clu, const int* __restrict__ offs,
                                                 int* __restrict__ cur, int* __restrict__ perm){
  int m = blockIdx.x*256 + threadIdx.x;
  int n = clu[m];
  int p = atomicAdd(&cur[n], 1);
  perm[offs[n] + p] = m;
}

// ---------------- prep: W2T transpose + W21T = (Wp2@Ww1)^T + c0 (one launch) ----------------
__global__ __launch_bounds__(256) void k_prep(const float* __restrict__ Wp2, const float* __restrict__ Ww1,
                                              const float* __restrict__ bw1, const float* __restrict__ bp2,
                                              u16* __restrict__ W21T, float* __restrict__ c0,
                                              u16* __restrict__ W2T){
  int i = blockIdx.x*256 + threadIdx.x;   // grid 256 -> 65536
  int col = i >> 8, cp = i & 255;
  W2T[col*256 + cp] = fu(Wp2[cp*256 + col]);
  if(i < 4096){
    int c = i >> 4, j = i & 15;
    float a = 0.f;
    for(int c2=0;c2<256;c2++) a += Wp2[c*256+c2] * Ww1[c2*16+j];
    W21T[j*256 + c] = fu(a);
  }
  if(i < 16){
    float s = bw1[i];
    for(int c2=0;c2<256;c2++) s += bp2[c2] * Ww1[c2*16+i];
    c0[i] = s;
  }
}

// ---------------- A = coord@Wp1 (bf16 [N,256], no bias) ----------------
__global__ __launch_bounds__(256) void k_A(const float* __restrict__ coord, const float* __restrict__ Wp1,
                                           u16* __restrict__ A){
  int i = blockIdx.x*256 + threadIdx.x;
  int n = i >> 8, c = i & 255;
  float a = coord[n*3]*Wp1[c] + coord[n*3+1]*Wp1[256+c] + coord[n*3+2]*Wp1[512+c];
  A[i] = fu(a);
}

// ---------------- As = s1*A + t1 (in-place, after bn1stats) ----------------
__global__ __launch_bounds__(256) void k_Astar(u16* __restrict__ A, const float* __restrict__ s1,
                                               const float* __restrict__ t1){
  int i8 = (blockIdx.x*256 + threadIdx.x)*8;   // grid 2048 -> N*256
  int c0 = i8 & 255;
  union { i32x4 v; u16 a[8]; } u, o;
  u.v = *(const i32x4*)(A + i8);
  #pragma unroll
  for(int r=0;r<8;r++) o.a[r] = fu(s1[c0+r]*uf(u.a[r]) + t1[c0+r]);
  *(i32x4*)(A + i8) = o.v;
}

// ---------------- staging helpers ----------------
__device__ __forceinline__ void stage8(const float* p, u16* dst){
  f32x4 a = *(const f32x4*)p; f32x4 b = *(const f32x4*)(p+4);
  union { i32x4 v; u16 a[8]; } u;
  u.a[0]=fu(a[0]); u.a[1]=fu(a[1]); u.a[2]=fu(a[2]); u.a[3]=fu(a[3]);
  u.a[4]=fu(b[0]); u.a[5]=fu(b[1]); u.a[6]=fu(b[2]); u.a[7]=fu(b[3]);
  *(i32x4*)dst = u.v;
}
__device__ __forceinline__ void stage8(const u16* p, u16* dst){
  *(i32x4*)dst = *(const i32x4*)p;
}

// ---------------- MFMA GEMM + fused col stats (f32 pre-rounding) ----------------
template<typename AT, int KD>
__global__ __launch_bounds__(256) void k_gemm(const AT* __restrict__ Ag, const float* __restrict__ Bg,
                                              const float* __restrict__ bias, u16* __restrict__ Y,
                                              float* __restrict__ sSum, float* __restrict__ sSq)
{
  __shared__ __align__(16) u16 At[64][40];
  __shared__ __align__(16) u16 Bt[64][40];   // [col][k]
  __shared__ float csum[64], csq[64];
  const int tid = threadIdx.x;
  const int lane = tid & 63, wv = tid >> 6;
  const int m0 = blockIdx.x * 64, n0 = blockIdx.y * 64;
  const int wr = (wv >> 1) * 32, wc = (wv & 1) * 32;
  const int fr = lane & 15, fq = lane >> 4, fk = fq * 8;
  f32x4 acc[2][2];
  acc[0][0]=acc[0][1]=acc[1][0]=acc[1][1]=(f32x4){0.f,0.f,0.f,0.f};
  const int arow = tid >> 2, akc = (tid & 3) * 8;
  const int brow = tid >> 3, bcol = (tid & 7) * 8;
  for(int k0 = 0; k0 < KD; k0 += 32){
    stage8(Ag + (size_t)(m0 + arow) * KD + k0 + akc, &At[arow][akc]);
    const float* bp = Bg + (size_t)(k0 + brow) * 256 + n0 + bcol;
    f32x4 b0 = *(const f32x4*)bp, b1 = *(const f32x4*)(bp+4);
    #pragma unroll
    for(int i=0;i<4;i++){ Bt[bcol + i][brow] = fu(b0[i]); Bt[bcol + 4 + i][brow] = fu(b1[i]); }
    __syncthreads();
    s16x8 af0 = *(const s16x8*)(&At[wr + fr][fk]);
    s16x8 af1 = *(const s16x8*)(&At[wr + 16 + fr][fk]);
    s16x8 bf0 = *(const s16x8*)(&Bt[wc + fr][fk]);
    s16x8 bf1 = *(const s16x8*)(&Bt[wc + 16 + fr][fk]);
    acc[0][0] = __builtin_amdgcn_mfma_f32_16x16x32_bf16(af0, bf0, acc[0][0], 0,0,0);
    acc[0][1] = __builtin_amdgcn_mfma_f32_16x16x32_bf16(af0, bf1, acc[0][1], 0,0,0);
    acc[1][0] = __builtin_amdgcn_mfma_f32_16x16x32_bf16(af1, bf0, acc[1][0], 0,0,0);
    acc[1][1] = __builtin_amdgcn_mfma_f32_16x16x32_bf16(af1, bf1, acc[1][1], 0,0,0);
    __syncthreads();
  }
  if(tid < 64){ csum[tid]=0.f; csq[tid]=0.f; }
  __syncthreads();
  #pragma unroll
  for(int ni=0; ni<2; ni++){
    const int lcol = wc + ni*16 + fr;
    const int col = n0 + lcol;
    const float bval = bias[col];
    float ps = 0.f, pq = 0.f;
    #pragma unroll
    for(int mi=0; mi<2; mi++){
      #pragma unroll
      for(int r=0; r<4; r++){
        const int row = m0 + wr + mi*16 + fq*4 + r;
        float v = acc[mi][ni][r] + bval;
        Y[(size_t)row*256 + col] = fu(v);
        ps += v; pq += v*v;
      }
    }
    atomicAdd(&csum[lcol], ps);
    atomicAdd(&csq[lcol], pq);
  }
  __syncthreads();
  if(tid < 64){
    atomicAdd(&sSum[n0 + tid], csum[tid]);
    atomicAdd(&sSq [n0 + tid], csq[tid]);
  }
}

// ---------------- BN finalize ----------------
__global__ void k_fin(const float* __restrict__ sum, const float* __restrict__ sq,
                      const float* __restrict__ gam, const float* __restrict__ bet,
                      float invn, int Cn, float* __restrict__ s, float* __restrict__ t){
  int c = threadIdx.x;
  if(c < Cn){
    float m = sum[c]*invn, v = sq[c]*invn - m*m;
    float sc = gam[c] * rsqrtf(v + EPS);
    s[c] = sc;
    t[c] = bet[c] - m*sc;
  }
}

// ---------------- lres = relu(bn(Yp)) ----------------
__global__ __launch_bounds__(256) void k_lres(const u16* __restrict__ Y, const float* __restrict__ s,
                                              const float* __restrict__ t, u16* __restrict__ lres){
  int i8 = (blockIdx.x*256 + threadIdx.x)*8;
  int c0 = i8 & 255;
  union { i32x4 v; u16 a[8]; } yu, ou;
  yu.v = *(const i32x4*)(Y + i8);
  #pragma unroll
  for(int r=0;r<8;r++) ou.a[r] = fu(fmaxf(s[c0+r]*uf(yu.a[r]) + t[c0+r], 0.f));
  *(i32x4*)(lres + i8) = ou.v;
}

// ---------------- skipP = relu(bn(Ys)); hres = skipP + lres[cluster] ----------------
__global__ __launch_bounds__(256) void k_hres(const u16* __restrict__ Ys, const float* __restrict__ s,
                                              const float* __restrict__ t, const u16* __restrict__ lres,
                                              const int* __restrict__ cluster,
                                              u16* __restrict__ skipP, u16* __restrict__ hres){
  int i8 = (blockIdx.x*256 + threadIdx.x)*8;
  int m = i8 >> 8, c0 = i8 & 255;
  int n = cluster[m];
  union { i32x4 v; u16 a[8]; } yu, lu, su, hu;
  yu.v = *(const i32x4*)(Ys + i8);
  lu.v = *(const i32x4*)(lres + (size_t)n*256 + c0);
  #pragma unroll
  for(int r=0;r<8;r++){
    float v = fmaxf(s[c0+r]*uf(yu.a[r]) + t[c0+r], 0.f);
    su.a[r] = fu(v);
    hu.a[r] = fu(v + uf(lu.a[r]));
  }
  *(i32x4*)(skipP + i8) = su.v;
  *(i32x4*)(hres  + i8) = hu.v;
}

// ---------------- proj16 (MFMA): Out[r][j] = relu(bn(Y[r,:])) @ Ww1 ----------------
__global__ __launch_bounds__(256) void k_proj16m(const u16* __restrict__ Y, const float* __restrict__ s,
                                                 const float* __restrict__ t, const float* __restrict__ Ww1,
                                                 float* __restrict__ Out){
  __shared__ __align__(16) u16 ub[64][264];    // bn-applied rows, bf16
  __shared__ __align__(16) u16 w1t[16][264];   // Ww1T[j][c], k-contiguous
  __shared__ float ssb[256], ttb[256];
  const int tid = threadIdx.x, lane = tid & 63, wv = tid >> 6;
  ssb[tid] = s[tid]; ttb[tid] = t[tid];
  for(int idx = tid; idx < 4096; idx += 256) w1t[idx & 15][idx >> 4] = fu(Ww1[idx]);
  __syncthreads();
  const int fj = lane & 15, fkb = (lane >> 4) * 8;
  s16x8 bfr[8];
  #pragma unroll
  for(int q=0;q<8;q++) bfr[q] = *(const s16x8*)(&w1t[fj][fkb + 32*q]);
  const int r0 = blockIdx.x * 64;
  const int srow = tid >> 2, sc0 = (tid & 3) * 64;
  const u16* yrow = Y + (size_t)(r0 + srow)*256 + sc0;
  #pragma unroll
  for(int b8=0;b8<8;b8++){
    union { i32x4 v; u16 a[8]; } yv, uv;
    yv.v = *(const i32x4*)(yrow + b8*8);
    #pragma unroll
    for(int e=0;e<8;e++){
      int c = sc0 + b8*8 + e;
      uv.a[e] = fu(fmaxf(ssb[c]*uf(yv.a[e]) + ttb[c], 0.f));
    }
    *(i32x4*)(&ub[srow][sc0 + b8*8]) = uv.v;
  }
  __syncthreads();
  f32x4 acc = (f32x4){0.f,0.f,0.f,0.f};
  #pragma unroll
  for(int q=0;q<8;q++){
    s16x8 af = *(const s16x8*)(&ub[wv*16 + fj][fkb + 32*q]);
    acc = __builtin_amdgcn_mfma_f32_16x16x32_bf16(af, bfr[q], acc, 0,0,0);
  }
  #pragma unroll
  for(int r=0;r<4;r++){
    int row = r0 + wv*16 + (lane>>4)*4 + r;
    Out[(size_t)row*16 + fj] = acc[r];
  }
}

// ---------------- BN1 stats, cluster-dedup (cached sa/sq per leader) ----------------
__global__ __launch_bounds__(256) void k_bn1stats(const u16* __restrict__ A, const int* __restrict__ ri,
                                                  const int* __restrict__ clu, const float* __restrict__ skc,
                                                  const float* __restrict__ Wp1, const int* __restrict__ perm,
                                                  float* __restrict__ bs, float* __restrict__ bq){
  __shared__ int refs[4][16];
  __shared__ float scs[4][3];
  __shared__ int lead4[4];
  const int c = threadIdx.x;
  const float w0 = Wp1[c], w1 = Wp1[256+c], w2 = Wp1[512+c];
  float S=0.f, Q=0.f;
  float sa16=0.f, sq16=0.f;
  const int i0 = blockIdx.x*64;           // grid 1024 x 64 = M
  for(int i = i0; i < i0+64; i += 4){
    if(c < 64){ int ml = c>>4, k = c&15; refs[ml][k] = ri[(size_t)clu[perm[i+ml]]*16 + k]; }
    else if(c < 80){ int q = c-64; int ml = q>>2, d = q&3;
      if(d < 3) scs[ml][d] = skc[(size_t)perm[i+ml]*3 + d]; }
    else if(c < 84){ int q = c-80;
      int n = clu[perm[i+q]];
      int ld = q;
      for(int j=0;j<q;j++) if(clu[perm[i+j]] == n){ ld = j; break; }
      lead4[q] = ld; }
    __syncthreads();
    #pragma unroll
    for(int ml=0; ml<4; ml++){
      if(lead4[ml] == ml){
        sa16 = 0.f; sq16 = 0.f;
        #pragma unroll
        for(int k=0;k<16;k++){
          float a = uf(A[(size_t)refs[ml][k]*256 + c]);
          sa16 += a; sq16 += a*a;
        }
      }
      float b = scs[ml][0]*w0 + scs[ml][1]*w1 + scs[ml][2]*w2;
      S += sa16 - 16.f*b;
      Q += sq16 - 2.f*b*sa16 + 16.f*b*b;
    }
    __syncthreads();
  }
  atomicAdd(&bs[c], S);
  atomicAdd(&bq[c], Q);
}

// ---------------- S2 (MFMA) + fused BN2 stats; intra-wave phase1->phase2, setprio ----------------
__global__ __launch_bounds__(256) void k_S2h(const u16* __restrict__ As, const int* __restrict__ ri,
    const int* __restrict__ clu, const float* __restrict__ skc, const float* __restrict__ Wp1,
    const float* __restrict__ s1,
    const float* __restrict__ KW, const float* __restrict__ QW,
    const u16* __restrict__ W21T, const float* __restrict__ c0,
    const int* __restrict__ perm, u16* __restrict__ w1out, float* __restrict__ st)
{
  __shared__ int refs[4][16];
  __shared__ float scm[4][3];
  __shared__ __align__(16) u16 hb[4][16][264];   // [ml][k][c] bf16
  __shared__ __align__(16) u16 w21t[16][264];    // [j][c] bf16
  __shared__ __align__(16) float bs2[4][260];    // s1*b per (ml,c)
  __shared__ float r2s[16][17], r2q[16][17];
  const int tid = threadIdx.x, lane = tid & 63, wv = tid >> 6;
  for(int idx = tid; idx < 4096; idx += 256)
    w21t[idx>>8][idx&255] = W21T[idx];
  const int c = tid;
  const float w0 = Wp1[c], w1v = Wp1[256+c], w2v = Wp1[512+c];
  const float s1c = s1[c];
  const int fj = lane & 15, fkb = (lane >> 4) * 8;
  const float c0j = c0[fj];
  const int ml4 = tid >> 6, kk = (tid >> 2) & 15, cp = tid & 3;
  __syncthreads();
  s16x8 bfr[8];
  #pragma unroll
  for(int s=0;s<8;s++) bfr[s] = *(const s16x8*)(&w21t[fj][fkb + 32*s]);
  float ls = 0.f, lq = 0.f;
  for(int ch = blockIdx.x; ch < MM/4; ch += gridDim.x){   // 8 iters
    const int base = ch*4;
    if(tid < 64){ int ml = tid>>4, k = tid&15; refs[ml][k] = ri[(size_t)clu[perm[base+ml]]*16 + k]; }
    else if(tid < 80){ int q = tid-64; int ml = q>>2, d = q&3;
      if(d < 3) scm[ml][d] = skc[(size_t)perm[base+ml]*3 + d]; }
    __syncthreads();
    #pragma unroll
    for(int ml=0; ml<4; ml++)
      bs2[ml][c] = s1c*(scm[ml][0]*w0 + scm[ml][1]*w1v + scm[ml][2]*w2v);
    __syncthreads();
    // phase1: wave wv builds hb[wv] — intra-wave with phase2, NO barrier after
    {
      const u16* arow = As + (size_t)refs[ml4][kk]*256 + cp*64;
      u16* hrow = &hb[ml4][kk][cp*64];
      const float* brow = &bs2[ml4][cp*64];
      #pragma unroll
      for(int b8=0;b8<8;b8++){
        union { i32x4 v; u16 a[8]; } av, hv;
        av.v = *(const i32x4*)(arow + b8*8);
        f32x4 b0 = *(const f32x4*)(brow + b8*8);
        f32x4 b1 = *(const f32x4*)(brow + b8*8 + 4);
        hv.a[0] = fu(fmaxf(uf(av.a[0]) - b0[0], 0.f));
        hv.a[1] = fu(fmaxf(uf(av.a[1]) - b0[1], 0.f));
        hv.a[2] = fu(fmaxf(uf(av.a[2]) - b0[2], 0.f));
        hv.a[3] = fu(fmaxf(uf(av.a[3]) - b0[3], 0.f));
        hv.a[4] = fu(fmaxf(uf(av.a[4]) - b1[0], 0.f));
        hv.a[5] = fu(fmaxf(uf(av.a[5]) - b1[1], 0.f));
        hv.a[6] = fu(fmaxf(uf(av.a[6]) - b1[2], 0.f));
        hv.a[7] = fu(fmaxf(uf(av.a[7]) - b1[3], 0.f));
        *(i32x4*)(hrow + b8*8) = hv.v;
      }
    }
    // phase2 (same wave consumes hb[wv]); setprio around MFMA cluster (T5)
    {
      const int m = perm[base + wv];
      f32x4 acc = (f32x4){0.f,0.f,0.f,0.f};
      __builtin_amdgcn_s_setprio(1);
      #pragma unroll
      for(int s=0;s<8;s++){
        s16x8 af = *(const s16x8*)(&hb[wv][fj][fkb + 32*s]);
        acc = __builtin_amdgcn_mfma_f32_16x16x32_bf16(af, bfr[s], acc, 0,0,0);
      }
      __builtin_amdgcn_s_setprio(0);
      #pragma unroll
      for(int r=0;r<4;r++){
        int krow = (lane>>4)*4 + r;
        float v = acc[r] + c0j + KW[(size_t)refs[wv][krow]*16 + fj] - QW[(size_t)m*16 + fj];
        w1out[(size_t)m*256 + krow*16 + fj] = fu(v);
        ls += v; lq += v*v;
      }
    }
    __syncthreads();
  }
  {
    const int slot = wv*4 + (lane>>4);   // 0..15, unique per fj
    r2s[fj][slot] = ls;
    r2q[fj][slot] = lq;
    __syncthreads();
    if(tid < 16){
      float a=0.f, b=0.f;
      #pragma unroll
      for(int i=0;i<16;i++){ a += r2s[tid][i]; b += r2q[tid][i]; }
      atomicAdd(&st[tid], a);
      atomicAdd(&st[16+tid], b);
    }
  }
}

// ---------------- F2t: fused F1 + MFMA T-build + MFMA phase4; intra-wave, setprio ----------------
__global__ __launch_bounds__(256) void k_F2t(const u16* __restrict__ As, const int* __restrict__ ri,
    const int* __restrict__ clu, const float* __restrict__ skc, const float* __restrict__ Wp1,
    const float* __restrict__ s1,
    const u16* __restrict__ w1, const u16* __restrict__ W2T, const float* __restrict__ bp2,
    const u16* __restrict__ lres, const u16* __restrict__ skipP, const int* __restrict__ perm,
    const float* __restrict__ s2, const float* __restrict__ t2,
    const float* __restrict__ Ww2, const float* __restrict__ bw2,
    float* __restrict__ outp)
{
  __shared__ int mm[8];
  __shared__ int refs[8][16];
  __shared__ int leader[8];
  __shared__ float scm[8][3];
  __shared__ float bs2F[8][260];                  // s1*b per (ml, c)
  __shared__ __align__(16) u16 w2kT[8][16][40];   // [ml][g][k] bf16, k>=16 zero
  __shared__ __align__(16) u16 hkc[8][32][40];    // [ml][c'][k] bf16; also reused as ul f32
  __shared__ __align__(16) u16 Tb[8][17][40];     // bf16 T; reused as opeb f32[8][260]
  const int tid = threadIdx.x, lane = tid & 63, wv = tid >> 6;
  const float w0 = Wp1[tid], w1g = Wp1[256+tid], w2g = Wp1[512+tid];
  const float s1c = s1[tid];
  // ww2 column regs for the fused F1 (j = tid&15)
  float ww2c[16];
  #pragma unroll
  for(int g=0; g<16; g++) ww2c[g] = Ww2[g*16 + (tid & 15)];
  const float s2j = s2[tid & 15], t2j = t2[tid & 15], bw2j = bw2[tid & 15];
  // w2kT pads (k=16..31) zeroed once per block; never overwritten later
  for(int idx = tid; idx < 8*16; idx += 256){
    int ml = idx>>4, g = idx&15;
    #pragma unroll
    for(int k=16;k<32;k++) w2kT[ml][g][k] = 0;
  }
  for(int sb = 0; sb < 4; sb++){                  // grid 2048 x 4 slices x 8 = M
    const int base = (blockIdx.x*4 + sb)*8;
    if(tid < 8) mm[tid] = perm[base + tid];
    __syncthreads();
    if(tid < 128){ int ml = tid>>4, k = tid&15; refs[ml][k] = ri[(size_t)clu[mm[ml]]*16 + k]; }
    else if(tid < 160){ int q = tid-128; int ml = q>>2, d = q&3; if(d<3) scm[ml][d] = skc[(size_t)mm[ml]*3 + d]; }
    else if(tid < 168){ int q = tid-160;
      int n = clu[mm[q]];
      int ld = q;
      for(int j=0;j<q;j++) if(clu[mm[j]] == n){ ld = j; break; }
      leader[q] = ld; }
    // fused F1 stage A: ul[ml][k][j] = relu(bn2(w1[m][k*16+j])) into hkc region
    {
      float* ulp = (float*)&hkc[0][0][0];     // ul(ml,k,j) = ulp[ml*272 + k*17 + j]
      const int mlu = tid >> 5, ju = tid & 15, khu = (tid >> 4) & 1;
      const u16* wrow = w1 + (size_t)mm[mlu]*256 + khu*128 + ju;
      #pragma unroll
      for(int i=0;i<8;i++){
        int k = khu*8 + i;
        float v = uf(wrow[i*16]);
        ulp[mlu*272 + k*17 + ju] = fmaxf(s2j*v + t2j, 0.f);
      }
    }
    __syncthreads();
    // fused F1 stage B: w2 + softmax -> w2kT[ml][j][k]; bs2F (independent)
    if(tid < 128){
      const int mlw = tid >> 4, jw = tid & 15;
      const float* ulp = (const float*)&hkc[0][0][0];
      float w2v[16];
      float mx = -1e30f;
      #pragma unroll
      for(int k=0;k<16;k++){
        float a = bw2j;
        #pragma unroll
        for(int g=0; g<16; g++) a += ulp[mlw*272 + k*17 + g]*ww2c[g];
        w2v[k] = a; mx = fmaxf(mx, a);
      }
      float den = 0.f;
      #pragma unroll
      for(int k=0;k<16;k++){ w2v[k] = __expf(w2v[k]-mx); den += w2v[k]; }
      float inv = 1.f/den;
      #pragma unroll
      for(int k=0;k<16;k++) w2kT[mlw][jw][k] = fu(w2v[k]*inv);
    }
    #pragma unroll
    for(int ml=0; ml<8; ml++)
      bs2F[ml][tid] = s1c*(scm[ml][0]*w0 + scm[ml][1]*w1g + scm[ml][2]*w2g);
    f32x4 accG[4];
    #pragma unroll
    for(int gi=0; gi<4; gi++) accG[gi] = (f32x4){0.f,0.f,0.f,0.f};
    __syncthreads();
    for(int q=0; q<8; q++){
      // phase1: wave wv gathers h for ml = 2wv..2wv+1 into hkc (intra-wave with phase3)
      {
        const int cl = tid & 31, mlh = tid >> 5;
        const int cg = q*32 + cl;
        const float bsv = bs2F[mlh][cg];
        union { i32x4 v[2]; u16 a[16]; } hr;
        #pragma unroll
        for(int k=0;k<16;k++){
          float a = uf(As[(size_t)refs[mlh][k]*256 + cg]);
          hr.a[k] = fu(fmaxf(a - bsv, 0.f));
        }
        *(i32x4*)(&hkc[mlh][cl][0])  = hr.v[0];
        *(i32x4*)(&hkc[mlh][cl][8])  = hr.v[1];
        *(i32x4*)(&hkc[mlh][cl][16]) = (i32x4){0,0,0,0};
        *(i32x4*)(&hkc[mlh][cl][24]) = (i32x4){0,0,0,0};
      }
      // NO barrier: phase3 wave wv reads exactly hkc[2wv..2wv+1] it just wrote
      __builtin_amdgcn_s_setprio(1);
      #pragma unroll
      for(int mq=0; mq<2; mq++){
        const int ml = wv*2 + mq;
        #pragma unroll
        for(int ct=0; ct<2; ct++){
          s16x8 af = *(const s16x8*)(&w2kT[ml][lane & 15][(lane>>4)*8]);
          s16x8 bf = *(const s16x8*)(&hkc[ml][ct*16 + (lane & 15)][(lane>>4)*8]);
          f32x4 d = __builtin_amdgcn_mfma_f32_16x16x32_bf16(af, bf, (f32x4){0.f,0.f,0.f,0.f}, 0,0,0);
          #pragma unroll
          for(int r=0;r<4;r++){
            int g = (lane>>4)*4 + r;
            Tb[ml][g][ct*16 + (lane & 15)] = fu(d[r]);
          }
        }
      }
      __builtin_amdgcn_s_setprio(0);
      __syncthreads();
      // phase4 (MFMA): accG += T @ W2T  (Tb cross-wave); setprio around cluster
      __builtin_amdgcn_s_setprio(1);
      #pragma unroll
      for(int gi=0; gi<4; gi++){
        const int g = wv*4 + gi;
        s16x8 tf = (s16x8){0,0,0,0,0,0,0,0};
        if((lane & 15) < 8)
          tf = *(const s16x8*)(&Tb[lane & 15][g][(lane>>4)*8]);
        s16x8 pf = *(const s16x8*)(&W2T[(size_t)(g*16 + (lane & 15))*256 + q*32 + (lane>>4)*8]);
        accG[gi] = __builtin_amdgcn_mfma_f32_16x16x32_bf16(tf, pf, accG[gi], 0,0,0);
      }
      __builtin_amdgcn_s_setprio(0);
      __syncthreads();
    }
    float* opeb = (float*)&Tb[0][0][0];
    #pragma unroll
    for(int gi=0; gi<4; gi++){
      const int g = wv*4 + gi;
      #pragma unroll
      for(int r=0;r<4;r++){
        int ml = (lane>>4)*4 + r;
        if(ml < 8) opeb[ml*260 + g*16 + (lane & 15)] = accG[gi][r];
      }
    }
    __syncthreads();
    // phase5: leader-dedup lres gathers
    {
      const int cc = tid, g = cc>>4;
      const float bp2c = bp2[cc];
      u16 lv[16];
      #pragma unroll
      for(int ml=0; ml<8; ml++){
        if(leader[ml] == ml){
          #pragma unroll
          for(int k=0;k<16;k++) lv[k] = lres[(size_t)refs[ml][k]*256 + cc];
        }
        union { s16x8 v; u16 a[8]; } wr0, wr1;
        wr0.v = *(const s16x8*)(&w2kT[ml][g][0]);
        wr1.v = *(const s16x8*)(&w2kT[ml][g][8]);
        float ol0 = 0.f, ol1 = 0.f;
        #pragma unroll
        for(int k=0;k<8;k++){
          ol0 += uf(wr0.a[k])*uf(lv[k]);
          ol1 += uf(wr1.a[k])*uf(lv[k+8]);
        }
        size_t m = (size_t)mm[ml];
        outp[m*256 + cc] = opeb[ml*260 + cc] + bp2c + (ol0 + ol1) + uf(skipP[m*256 + cc]);
      }
    }
    __syncthreads();
  }
}

// ---------------------------------------------------------------------------
extern "C" void kernel_launch(void* const* d_in, const int* in_sizes, int n_in,
                              void* d_out, int out_size, void* d_ws, size_t ws_size,
                              hipStream_t stream){
  (void)in_sizes; (void)n_in;
  const float *coord=(const float*)d_in[0], *feat=(const float*)d_in[1];
  const float *skc=(const float*)d_in[2],   *skf=(const float*)d_in[3];
  const int *clu=(const int*)d_in[4],   *ri=(const int*)d_in[5];
  const float *Wp=(const float*)d_in[6],  *bp=(const float*)d_in[7],  *gp=(const float*)d_in[8],  *bep=(const float*)d_in[9];
  const float *Wsk=(const float*)d_in[10],*bs=(const float*)d_in[11], *gs=(const float*)d_in[12], *bes=(const float*)d_in[13];
  const float *Wk=(const float*)d_in[14], *bk=(const float*)d_in[15], *gk=(const float*)d_in[16], *bek=(const float*)d_in[17];
  const float *Wq=(const float*)d_in[18], *bq=(const float*)d_in[19], *gq=(const float*)d_in[20], *beq=(const float*)d_in[21];
  const float *Wp1=(const float*)d_in[22],                           *gp1=(const float*)d_in[24], *bep1=(const float*)d_in[25];
  const float *Wp2=(const float*)d_in[26], *bp2=(const float*)d_in[27];
  const float *Ww1=(const float*)d_in[28], *bw1=(const float*)d_in[29], *gw1=(const float*)d_in[30], *bew1=(const float*)d_in[31];
  const float *Ww2=(const float*)d_in[32], *bw2=(const float*)d_in[33];

  constexpr size_t OFF_A    = 0;          // bf16 [N,256]  A -> As (in-place)
  constexpr size_t OFF_LRES = 8388608;    // bf16 [N,256]
  constexpr size_t OFF_NY   = 16777216;   // bf16 [N,256]  Yp->Yk, then sort scratch
  constexpr size_t OFF_SKP  = 25165824;   // bf16 [M,256]
  constexpr size_t OFF_M1   = 58720256;   // bf16 [M,256]  Ys->Yq->w1raw
  constexpr size_t OFF_M2   = 92274688;   // bf16 [M,256]  hres
  constexpr size_t OFF_KW   = 125829120;  // f32 [N,16]
  constexpr size_t OFF_QW   = 126877696;  // f32 [M,16]
  constexpr size_t OFF_ACC  = 131072000;  // f32 accumulators (zeroed)
  constexpr size_t OFF_PAR  = 131084288;  // f32 params (+ bf16 W21T)
  constexpr size_t OFF_W2T  = 131117056;  // bf16 [256][256] Wp2 transposed
  constexpr size_t NEED     = 131248128;

  if(ws_size < NEED){
    k_fill<<<65536, 256, 0, stream>>>((float*)d_out, out_size);
    return;
  }
  char* ws = (char*)d_ws;
  u16* Ab    = (u16*)(ws + OFF_A);
  u16* lresb = (u16*)(ws + OFF_LRES);
  u16* nY    = (u16*)(ws + OFF_NY);
  u16* skipP = (u16*)(ws + OFF_SKP);
  u16* M1    = (u16*)(ws + OFF_M1);
  u16* M2    = (u16*)(ws + OFF_M2);
  float* KWp = (float*)(ws + OFF_KW);
  float* QWp = (float*)(ws + OFF_QW);
  u16* W2Tp  = (u16*)(ws + OFF_W2T);
  int* cntp  = (int*)(ws + OFF_NY);             // 16384 i32 (also cursor)
  int* offsp = (int*)(ws + OFF_NY + 65536);     // 16384 i32
  int* permp = (int*)(ws + OFF_NY + 131072);    // 65536 i32
  float* ACC = (float*)(ws + OFF_ACC);
  float *gs0 = ACC+0,    *gq0 = ACC+256;
  float *gs1 = ACC+512,  *gq1 = ACC+768;
  float *gs2 = ACC+1024, *gq2 = ACC+1280;
  float *gs3 = ACC+1536, *gq3 = ACC+1792;
  float *b1s = ACC+2048, *b1q = ACC+2304;
  float *b2s = ACC+2560; // b2q = b2s+16
  float* PAR = (float*)(ws + OFF_PAR);
  float *sB0 = PAR+0,    *tB0 = PAR+256;
  float *sB1 = PAR+512,  *tB1 = PAR+768;
  float *sB2 = PAR+1024, *tB2 = PAR+1280;
  float *sB3 = PAR+1536, *tB3 = PAR+1792;
  float *s1p = PAR+2048, *t1p = PAR+2304;
  float *s2p = PAR+2560, *t2p = PAR+2576;
  float *c0p = PAR+2592;
  u16  *W21Tp= (u16*)(PAR+2608);  // bf16 [16][256] = 8 KB

  hipMemsetAsync(ws + OFF_ACC, 0, 12288, stream);

  k_prep<<<256, 256, 0, stream>>>(Wp2, Ww1, bw1, bp2, W21Tp, c0p, W2Tp);
  k_A<<<16384, 256, 0, stream>>>(coord, Wp1, Ab);

  // proj: Yp = feat@Wp + bp  -> lres   (stats fused in gemm)
  k_gemm<float,256><<<dim3(256,4), 256, 0, stream>>>(feat, Wp, bp, nY, gs0, gq0);
  k_fin<<<1, 256, 0, stream>>>(gs0, gq0, gp, bep, 1.f/(float)NN, 256, sB0, tB0);
  k_lres<<<2048, 256, 0, stream>>>(nY, sB0, tB0, lresb);

  // proj_skip: Ys = skf@Ws + bs -> skipP, hres
  k_gemm<float,128><<<dim3(1024,4), 256, 0, stream>>>(skf, Wsk, bs, M1, gs1, gq1);
  k_fin<<<1, 256, 0, stream>>>(gs1, gq1, gs, bes, 1.f/(float)MM, 256, sB1, tB1);
  k_hres<<<8192, 256, 0, stream>>>(M1, sB1, tB1, lresb, clu, skipP, M2);

  // key: Yk = lres@Wk + bk; KW = relu(bn(Yk))@Ww1  (MFMA proj16)
  k_gemm<u16,256><<<dim3(256,4), 256, 0, stream>>>(lresb, Wk, bk, nY, gs2, gq2);
  k_fin<<<1, 256, 0, stream>>>(gs2, gq2, gk, bek, 1.f/(float)NN, 256, sB2, tB2);
  k_proj16m<<<256, 256, 0, stream>>>(nY, sB2, tB2, Ww1, KWp);   // last nY use

  // counting sort of m by cluster
  hipMemsetAsync(cntp, 0, 65536, stream);
  k_count<<<256, 256, 0, stream>>>(clu, cntp);
  k_scan<<<1, 256, 0, stream>>>(cntp, offsp);
  k_scatter<<<256, 256, 0, stream>>>(clu, offsp, cntp, permp);

  // query: Yq = hres@Wq + bq; QW = relu(bn(Yq))@Ww1  (MFMA proj16)
  k_gemm<u16,256><<<dim3(1024,4), 256, 0, stream>>>(M2, Wq, bq, M1, gs3, gq3);
  k_fin<<<1, 256, 0, stream>>>(gs3, gq3, gq, beq, 1.f/(float)MM, 256, sB3, tB3);
  k_proj16m<<<1024, 256, 0, stream>>>(M1, sB3, tB3, Ww1, QWp);

  // BN1 (cluster-dedup stats on raw A), then fold affine into A (A -> As)
  k_bn1stats<<<1024, 256, 0, stream>>>(Ab, ri, clu, skc, Wp1, permp, b1s, b1q);
  k_fin<<<1, 256, 0, stream>>>(b1s, b1q, gp1, bep1, 1.f/(float)MKCNT, 256, s1p, t1p);
  k_Astar<<<2048, 256, 0, stream>>>(Ab, s1p, t1p);

  // w1raw (MFMA S2 + fused BN2 stats, intra-wave phase1->phase2, setprio)
  k_S2h<<<2048, 256, 0, stream>>>(Ab, ri, clu, skc, Wp1, s1p, KWp, QWp, W21Tp, c0p, permp, M1, b2s);
  k_fin<<<1, 256, 0, stream>>>(b2s, b2s+16, gw1, bew1, 1.f/(float)MKCNT, 16, s2p, t2p);

  // final output (F1 fused; intra-wave phase1->phase3, setprio)
  k_F2t<<<2048, 256, 0, stream>>>(Ab, ri, clu, skc, Wp1, s1p, M1, W2Tp, bp2, lresb, skipP, permp,
                                  s2p, t2p, Ww2, bw2, (float*)d_out);
}

// Round 25
// 861.774 us; speedup vs baseline: 1.0299x; 1.0299x over previous
//
#include <hip/hip_runtime.h>

// ---------------------------------------------------------------------------
// UnpoolWithSkip — round 25: FINAL — revert to round-23 verbatim (measured
// best, 872.9us). r24's setprio regressed (-15us): with 2 barriers/chunk the
// role-diversity window is too short; boosting MFMA waves delays sibling
// gather issue (the true critical path). Search closed from 5 angles:
// prefetch(-), LDS-occupancy(-), issue-trims(0), barrier-trim(+6, kept),
// setprio(-). k_F2t is dependent-gather latency-bound at 31% occupancy;
// HBM 9%/MFMA 4% — a latency local-minimum, not a hardware roofline.
// ---------------------------------------------------------------------------

typedef unsigned short u16;
typedef unsigned int   u32;
typedef __attribute__((ext_vector_type(4))) float f32x4;
typedef __attribute__((ext_vector_type(8))) short s16x8;
typedef __attribute__((ext_vector_type(4))) int   i32x4;

#define NN 16384
#define MM 65536
#define MKCNT 1048576
#define EPS 1e-5f

__device__ __forceinline__ float uf(u16 u){ union{u32 i; float f;} x; x.i = ((u32)u)<<16; return x.f; }
__device__ __forceinline__ u16 fu(float f){ u32 x = __float_as_uint(f); u32 r = (x + 0x7fffu + ((x>>16)&1u))>>16; return (u16)r; }

__global__ void k_fill(float* o, int nsz){
  int i = blockIdx.x*256 + threadIdx.x;
  if(i < nsz) o[i] = 12345.0f;
}

// ---------------- counting sort by cluster ----------------
__global__ __launch_bounds__(256) void k_count(const int* __restrict__ clu, int* __restrict__ cnt){
  int m = blockIdx.x*256 + threadIdx.x;
  atomicAdd(&cnt[clu[m]], 1);
}
__global__ __launch_bounds__(256) void k_scan(int* __restrict__ cnt, int* __restrict__ offs){
  __shared__ int part[256];
  int t = threadIdx.x;
  int s = 0;
  #pragma unroll 1
  for(int i=0;i<64;i++) s += cnt[t*64+i];
  part[t] = s;
  __syncthreads();
  if(t==0){ int run=0; for(int i=0;i<256;i++){ int tmp=part[i]; part[i]=run; run+=tmp; } }
  __syncthreads();
  int run = part[t];
  #pragma unroll 1
  for(int i=0;i<64;i++){ int c = cnt[t*64+i]; offs[t*64+i] = run; run += c; cnt[t*64+i] = 0; }
}
__global__ __launch_bounds__(256) void k_scatter(const int* __restrict__ clu, const int* __restrict__ offs,
                                                 int* __restrict__ cur, int* __restrict__ perm){
  int m = blockIdx.x*256 + threadIdx.x;
  int n = clu[m];
  int p = atomicAdd(&cur[n], 1);
  perm[offs[n] + p] = m;
}

// ---------------- prep: W2T transpose + W21T = (Wp2@Ww1)^T + c0 (one launch) ----------------
__global__ __launch_bounds__(256) void k_prep(const float* __restrict__ Wp2, const float* __restrict__ Ww1,
                                              const float* __restrict__ bw1, const float* __restrict__ bp2,
                                              u16* __restrict__ W21T, float* __restrict__ c0,
                                              u16* __restrict__ W2T){
  int i = blockIdx.x*256 + threadIdx.x;   // grid 256 -> 65536
  int col = i >> 8, cp = i & 255;
  W2T[col*256 + cp] = fu(Wp2[cp*256 + col]);
  if(i < 4096){
    int c = i >> 4, j = i & 15;
    float a = 0.f;
    for(int c2=0;c2<256;c2++) a += Wp2[c*256+c2] * Ww1[c2*16+j];
    W21T[j*256 + c] = fu(a);
  }
  if(i < 16){
    float s = bw1[i];
    for(int c2=0;c2<256;c2++) s += bp2[c2] * Ww1[c2*16+i];
    c0[i] = s;
  }
}

// ---------------- A = coord@Wp1 (bf16 [N,256], no bias) ----------------
__global__ __launch_bounds__(256) void k_A(const float* __restrict__ coord, const float* __restrict__ Wp1,
                                           u16* __restrict__ A){
  int i = blockIdx.x*256 + threadIdx.x;
  int n = i >> 8, c = i & 255;
  float a = coord[n*3]*Wp1[c] + coord[n*3+1]*Wp1[256+c] + coord[n*3+2]*Wp1[512+c];
  A[i] = fu(a);
}

// ---------------- As = s1*A + t1 (in-place, after bn1stats) ----------------
__global__ __launch_bounds__(256) void k_Astar(u16* __restrict__ A, const float* __restrict__ s1,
                                               const float* __restrict__ t1){
  int i8 = (blockIdx.x*256 + threadIdx.x)*8;   // grid 2048 -> N*256
  int c0 = i8 & 255;
  union { i32x4 v; u16 a[8]; } u, o;
  u.v = *(const i32x4*)(A + i8);
  #pragma unroll
  for(int r=0;r<8;r++) o.a[r] = fu(s1[c0+r]*uf(u.a[r]) + t1[c0+r]);
  *(i32x4*)(A + i8) = o.v;
}

// ---------------- staging helpers ----------------
__device__ __forceinline__ void stage8(const float* p, u16* dst){
  f32x4 a = *(const f32x4*)p; f32x4 b = *(const f32x4*)(p+4);
  union { i32x4 v; u16 a[8]; } u;
  u.a[0]=fu(a[0]); u.a[1]=fu(a[1]); u.a[2]=fu(a[2]); u.a[3]=fu(a[3]);
  u.a[4]=fu(b[0]); u.a[5]=fu(b[1]); u.a[6]=fu(b[2]); u.a[7]=fu(b[3]);
  *(i32x4*)dst = u.v;
}
__device__ __forceinline__ void stage8(const u16* p, u16* dst){
  *(i32x4*)dst = *(const i32x4*)p;
}

// ---------------- MFMA GEMM + fused col stats (f32 pre-rounding) ----------------
template<typename AT, int KD>
__global__ __launch_bounds__(256) void k_gemm(const AT* __restrict__ Ag, const float* __restrict__ Bg,
                                              const float* __restrict__ bias, u16* __restrict__ Y,
                                              float* __restrict__ sSum, float* __restrict__ sSq)
{
  __shared__ __align__(16) u16 At[64][40];
  __shared__ __align__(16) u16 Bt[64][40];   // [col][k]
  __shared__ float csum[64], csq[64];
  const int tid = threadIdx.x;
  const int lane = tid & 63, wv = tid >> 6;
  const int m0 = blockIdx.x * 64, n0 = blockIdx.y * 64;
  const int wr = (wv >> 1) * 32, wc = (wv & 1) * 32;
  const int fr = lane & 15, fq = lane >> 4, fk = fq * 8;
  f32x4 acc[2][2];
  acc[0][0]=acc[0][1]=acc[1][0]=acc[1][1]=(f32x4){0.f,0.f,0.f,0.f};
  const int arow = tid >> 2, akc = (tid & 3) * 8;
  const int brow = tid >> 3, bcol = (tid & 7) * 8;
  for(int k0 = 0; k0 < KD; k0 += 32){
    stage8(Ag + (size_t)(m0 + arow) * KD + k0 + akc, &At[arow][akc]);
    const float* bp = Bg + (size_t)(k0 + brow) * 256 + n0 + bcol;
    f32x4 b0 = *(const f32x4*)bp, b1 = *(const f32x4*)(bp+4);
    #pragma unroll
    for(int i=0;i<4;i++){ Bt[bcol + i][brow] = fu(b0[i]); Bt[bcol + 4 + i][brow] = fu(b1[i]); }
    __syncthreads();
    s16x8 af0 = *(const s16x8*)(&At[wr + fr][fk]);
    s16x8 af1 = *(const s16x8*)(&At[wr + 16 + fr][fk]);
    s16x8 bf0 = *(const s16x8*)(&Bt[wc + fr][fk]);
    s16x8 bf1 = *(const s16x8*)(&Bt[wc + 16 + fr][fk]);
    acc[0][0] = __builtin_amdgcn_mfma_f32_16x16x32_bf16(af0, bf0, acc[0][0], 0,0,0);
    acc[0][1] = __builtin_amdgcn_mfma_f32_16x16x32_bf16(af0, bf1, acc[0][1], 0,0,0);
    acc[1][0] = __builtin_amdgcn_mfma_f32_16x16x32_bf16(af1, bf0, acc[1][0], 0,0,0);
    acc[1][1] = __builtin_amdgcn_mfma_f32_16x16x32_bf16(af1, bf1, acc[1][1], 0,0,0);
    __syncthreads();
  }
  if(tid < 64){ csum[tid]=0.f; csq[tid]=0.f; }
  __syncthreads();
  #pragma unroll
  for(int ni=0; ni<2; ni++){
    const int lcol = wc + ni*16 + fr;
    const int col = n0 + lcol;
    const float bval = bias[col];
    float ps = 0.f, pq = 0.f;
    #pragma unroll
    for(int mi=0; mi<2; mi++){
      #pragma unroll
      for(int r=0; r<4; r++){
        const int row = m0 + wr + mi*16 + fq*4 + r;
        float v = acc[mi][ni][r] + bval;
        Y[(size_t)row*256 + col] = fu(v);
        ps += v; pq += v*v;
      }
    }
    atomicAdd(&csum[lcol], ps);
    atomicAdd(&csq[lcol], pq);
  }
  __syncthreads();
  if(tid < 64){
    atomicAdd(&sSum[n0 + tid], csum[tid]);
    atomicAdd(&sSq [n0 + tid], csq[tid]);
  }
}

// ---------------- BN finalize ----------------
__global__ void k_fin(const float* __restrict__ sum, const float* __restrict__ sq,
                      const float* __restrict__ gam, const float* __restrict__ bet,
                      float invn, int Cn, float* __restrict__ s, float* __restrict__ t){
  int c = threadIdx.x;
  if(c < Cn){
    float m = sum[c]*invn, v = sq[c]*invn - m*m;
    float sc = gam[c] * rsqrtf(v + EPS);
    s[c] = sc;
    t[c] = bet[c] - m*sc;
  }
}

// ---------------- lres = relu(bn(Yp)) ----------------
__global__ __launch_bounds__(256) void k_lres(const u16* __restrict__ Y, const float* __restrict__ s,
                                              const float* __restrict__ t, u16* __restrict__ lres){
  int i8 = (blockIdx.x*256 + threadIdx.x)*8;
  int c0 = i8 & 255;
  union { i32x4 v; u16 a[8]; } yu, ou;
  yu.v = *(const i32x4*)(Y + i8);
  #pragma unroll
  for(int r=0;r<8;r++) ou.a[r] = fu(fmaxf(s[c0+r]*uf(yu.a[r]) + t[c0+r], 0.f));
  *(i32x4*)(lres + i8) = ou.v;
}

// ---------------- skipP = relu(bn(Ys)); hres = skipP + lres[cluster] ----------------
__global__ __launch_bounds__(256) void k_hres(const u16* __restrict__ Ys, const float* __restrict__ s,
                                              const float* __restrict__ t, const u16* __restrict__ lres,
                                              const int* __restrict__ cluster,
                                              u16* __restrict__ skipP, u16* __restrict__ hres){
  int i8 = (blockIdx.x*256 + threadIdx.x)*8;
  int m = i8 >> 8, c0 = i8 & 255;
  int n = cluster[m];
  union { i32x4 v; u16 a[8]; } yu, lu, su, hu;
  yu.v = *(const i32x4*)(Ys + i8);
  lu.v = *(const i32x4*)(lres + (size_t)n*256 + c0);
  #pragma unroll
  for(int r=0;r<8;r++){
    float v = fmaxf(s[c0+r]*uf(yu.a[r]) + t[c0+r], 0.f);
    su.a[r] = fu(v);
    hu.a[r] = fu(v + uf(lu.a[r]));
  }
  *(i32x4*)(skipP + i8) = su.v;
  *(i32x4*)(hres  + i8) = hu.v;
}

// ---------------- proj16 (MFMA): Out[r][j] = relu(bn(Y[r,:])) @ Ww1 ----------------
__global__ __launch_bounds__(256) void k_proj16m(const u16* __restrict__ Y, const float* __restrict__ s,
                                                 const float* __restrict__ t, const float* __restrict__ Ww1,
                                                 float* __restrict__ Out){
  __shared__ __align__(16) u16 ub[64][264];    // bn-applied rows, bf16
  __shared__ __align__(16) u16 w1t[16][264];   // Ww1T[j][c], k-contiguous
  __shared__ float ssb[256], ttb[256];
  const int tid = threadIdx.x, lane = tid & 63, wv = tid >> 6;
  ssb[tid] = s[tid]; ttb[tid] = t[tid];
  for(int idx = tid; idx < 4096; idx += 256) w1t[idx & 15][idx >> 4] = fu(Ww1[idx]);
  __syncthreads();
  const int fj = lane & 15, fkb = (lane >> 4) * 8;
  s16x8 bfr[8];
  #pragma unroll
  for(int q=0;q<8;q++) bfr[q] = *(const s16x8*)(&w1t[fj][fkb + 32*q]);
  const int r0 = blockIdx.x * 64;
  const int srow = tid >> 2, sc0 = (tid & 3) * 64;
  const u16* yrow = Y + (size_t)(r0 + srow)*256 + sc0;
  #pragma unroll
  for(int b8=0;b8<8;b8++){
    union { i32x4 v; u16 a[8]; } yv, uv;
    yv.v = *(const i32x4*)(yrow + b8*8);
    #pragma unroll
    for(int e=0;e<8;e++){
      int c = sc0 + b8*8 + e;
      uv.a[e] = fu(fmaxf(ssb[c]*uf(yv.a[e]) + ttb[c], 0.f));
    }
    *(i32x4*)(&ub[srow][sc0 + b8*8]) = uv.v;
  }
  __syncthreads();
  f32x4 acc = (f32x4){0.f,0.f,0.f,0.f};
  #pragma unroll
  for(int q=0;q<8;q++){
    s16x8 af = *(const s16x8*)(&ub[wv*16 + fj][fkb + 32*q]);
    acc = __builtin_amdgcn_mfma_f32_16x16x32_bf16(af, bfr[q], acc, 0,0,0);
  }
  #pragma unroll
  for(int r=0;r<4;r++){
    int row = r0 + wv*16 + (lane>>4)*4 + r;
    Out[(size_t)row*16 + fj] = acc[r];
  }
}

// ---------------- BN1 stats, cluster-dedup (cached sa/sq per leader) ----------------
__global__ __launch_bounds__(256) void k_bn1stats(const u16* __restrict__ A, const int* __restrict__ ri,
                                                  const int* __restrict__ clu, const float* __restrict__ skc,
                                                  const float* __restrict__ Wp1, const int* __restrict__ perm,
                                                  float* __restrict__ bs, float* __restrict__ bq){
  __shared__ int refs[4][16];
  __shared__ float scs[4][3];
  __shared__ int lead4[4];
  const int c = threadIdx.x;
  const float w0 = Wp1[c], w1 = Wp1[256+c], w2 = Wp1[512+c];
  float S=0.f, Q=0.f;
  float sa16=0.f, sq16=0.f;
  const int i0 = blockIdx.x*64;           // grid 1024 x 64 = M
  for(int i = i0; i < i0+64; i += 4){
    if(c < 64){ int ml = c>>4, k = c&15; refs[ml][k] = ri[(size_t)clu[perm[i+ml]]*16 + k]; }
    else if(c < 80){ int q = c-64; int ml = q>>2, d = q&3;
      if(d < 3) scs[ml][d] = skc[(size_t)perm[i+ml]*3 + d]; }
    else if(c < 84){ int q = c-80;
      int n = clu[perm[i+q]];
      int ld = q;
      for(int j=0;j<q;j++) if(clu[perm[i+j]] == n){ ld = j; break; }
      lead4[q] = ld; }
    __syncthreads();
    #pragma unroll
    for(int ml=0; ml<4; ml++){
      if(lead4[ml] == ml){
        sa16 = 0.f; sq16 = 0.f;
        #pragma unroll
        for(int k=0;k<16;k++){
          float a = uf(A[(size_t)refs[ml][k]*256 + c]);
          sa16 += a; sq16 += a*a;
        }
      }
      float b = scs[ml][0]*w0 + scs[ml][1]*w1 + scs[ml][2]*w2;
      S += sa16 - 16.f*b;
      Q += sq16 - 2.f*b*sa16 + 16.f*b*b;
    }
    __syncthreads();
  }
  atomicAdd(&bs[c], S);
  atomicAdd(&bq[c], Q);
}

// ---------------- S2 (MFMA) + fused BN2 stats; intra-wave phase1->phase2 ----------------
__global__ __launch_bounds__(256) void k_S2h(const u16* __restrict__ As, const int* __restrict__ ri,
    const int* __restrict__ clu, const float* __restrict__ skc, const float* __restrict__ Wp1,
    const float* __restrict__ s1,
    const float* __restrict__ KW, const float* __restrict__ QW,
    const u16* __restrict__ W21T, const float* __restrict__ c0,
    const int* __restrict__ perm, u16* __restrict__ w1out, float* __restrict__ st)
{
  __shared__ int refs[4][16];
  __shared__ float scm[4][3];
  __shared__ __align__(16) u16 hb[4][16][264];   // [ml][k][c] bf16
  __shared__ __align__(16) u16 w21t[16][264];    // [j][c] bf16
  __shared__ __align__(16) float bs2[4][260];    // s1*b per (ml,c)
  __shared__ float r2s[16][17], r2q[16][17];
  const int tid = threadIdx.x, lane = tid & 63, wv = tid >> 6;
  for(int idx = tid; idx < 4096; idx += 256)
    w21t[idx>>8][idx&255] = W21T[idx];
  const int c = tid;
  const float w0 = Wp1[c], w1v = Wp1[256+c], w2v = Wp1[512+c];
  const float s1c = s1[c];
  const int fj = lane & 15, fkb = (lane >> 4) * 8;
  const float c0j = c0[fj];
  const int ml4 = tid >> 6, kk = (tid >> 2) & 15, cp = tid & 3;
  __syncthreads();
  s16x8 bfr[8];
  #pragma unroll
  for(int s=0;s<8;s++) bfr[s] = *(const s16x8*)(&w21t[fj][fkb + 32*s]);
  float ls = 0.f, lq = 0.f;
  for(int ch = blockIdx.x; ch < MM/4; ch += gridDim.x){   // 8 iters
    const int base = ch*4;
    if(tid < 64){ int ml = tid>>4, k = tid&15; refs[ml][k] = ri[(size_t)clu[perm[base+ml]]*16 + k]; }
    else if(tid < 80){ int q = tid-64; int ml = q>>2, d = q&3;
      if(d < 3) scm[ml][d] = skc[(size_t)perm[base+ml]*3 + d]; }
    __syncthreads();
    #pragma unroll
    for(int ml=0; ml<4; ml++)
      bs2[ml][c] = s1c*(scm[ml][0]*w0 + scm[ml][1]*w1v + scm[ml][2]*w2v);
    __syncthreads();
    // phase1: wave wv builds hb[wv] (ml4 == wv) — intra-wave with phase2, NO barrier after
    {
      const u16* arow = As + (size_t)refs[ml4][kk]*256 + cp*64;
      u16* hrow = &hb[ml4][kk][cp*64];
      const float* brow = &bs2[ml4][cp*64];
      #pragma unroll
      for(int b8=0;b8<8;b8++){
        union { i32x4 v; u16 a[8]; } av, hv;
        av.v = *(const i32x4*)(arow + b8*8);
        f32x4 b0 = *(const f32x4*)(brow + b8*8);
        f32x4 b1 = *(const f32x4*)(brow + b8*8 + 4);
        hv.a[0] = fu(fmaxf(uf(av.a[0]) - b0[0], 0.f));
        hv.a[1] = fu(fmaxf(uf(av.a[1]) - b0[1], 0.f));
        hv.a[2] = fu(fmaxf(uf(av.a[2]) - b0[2], 0.f));
        hv.a[3] = fu(fmaxf(uf(av.a[3]) - b0[3], 0.f));
        hv.a[4] = fu(fmaxf(uf(av.a[4]) - b1[0], 0.f));
        hv.a[5] = fu(fmaxf(uf(av.a[5]) - b1[1], 0.f));
        hv.a[6] = fu(fmaxf(uf(av.a[6]) - b1[2], 0.f));
        hv.a[7] = fu(fmaxf(uf(av.a[7]) - b1[3], 0.f));
        *(i32x4*)(hrow + b8*8) = hv.v;
      }
    }
    // phase2 (same wave consumes hb[wv]; compiler lgkmcnt orders LDS ops)
    {
      const int m = perm[base + wv];
      f32x4 acc = (f32x4){0.f,0.f,0.f,0.f};
      #pragma unroll
      for(int s=0;s<8;s++){
        s16x8 af = *(const s16x8*)(&hb[wv][fj][fkb + 32*s]);
        acc = __builtin_amdgcn_mfma_f32_16x16x32_bf16(af, bfr[s], acc, 0,0,0);
      }
      #pragma unroll
      for(int r=0;r<4;r++){
        int krow = (lane>>4)*4 + r;
        float v = acc[r] + c0j + KW[(size_t)refs[wv][krow]*16 + fj] - QW[(size_t)m*16 + fj];
        w1out[(size_t)m*256 + krow*16 + fj] = fu(v);
        ls += v; lq += v*v;
      }
    }
    __syncthreads();
  }
  {
    const int slot = wv*4 + (lane>>4);   // 0..15, unique per fj
    r2s[fj][slot] = ls;
    r2q[fj][slot] = lq;
    __syncthreads();
    if(tid < 16){
      float a=0.f, b=0.f;
      #pragma unroll
      for(int i=0;i<16;i++){ a += r2s[tid][i]; b += r2q[tid][i]; }
      atomicAdd(&st[tid], a);
      atomicAdd(&st[16+tid], b);
    }
  }
}

// ---------------- F2t: fused F1 + MFMA T-build + MFMA phase4; intra-wave ph1->ph3 ----------------
__global__ __launch_bounds__(256) void k_F2t(const u16* __restrict__ As, const int* __restrict__ ri,
    const int* __restrict__ clu, const float* __restrict__ skc, const float* __restrict__ Wp1,
    const float* __restrict__ s1,
    const u16* __restrict__ w1, const u16* __restrict__ W2T, const float* __restrict__ bp2,
    const u16* __restrict__ lres, const u16* __restrict__ skipP, const int* __restrict__ perm,
    const float* __restrict__ s2, const float* __restrict__ t2,
    const float* __restrict__ Ww2, const float* __restrict__ bw2,
    float* __restrict__ outp)
{
  __shared__ int mm[8];
  __shared__ int refs[8][16];
  __shared__ int leader[8];
  __shared__ float scm[8][3];
  __shared__ float bs2F[8][260];                  // s1*b per (ml, c)
  __shared__ __align__(16) u16 w2kT[8][16][40];   // [ml][g][k] bf16, k>=16 zero
  __shared__ __align__(16) u16 hkc[8][32][40];    // [ml][c'][k] bf16; also reused as ul f32
  __shared__ __align__(16) u16 Tb[8][17][40];     // bf16 T; reused as opeb f32[8][260]
  const int tid = threadIdx.x, lane = tid & 63, wv = tid >> 6;
  const float w0 = Wp1[tid], w1g = Wp1[256+tid], w2g = Wp1[512+tid];
  const float s1c = s1[tid];
  // ww2 column regs for the fused F1 (j = tid&15)
  float ww2c[16];
  #pragma unroll
  for(int g=0; g<16; g++) ww2c[g] = Ww2[g*16 + (tid & 15)];
  const float s2j = s2[tid & 15], t2j = t2[tid & 15], bw2j = bw2[tid & 15];
  // w2kT pads (k=16..31) zeroed once per block; never overwritten later
  for(int idx = tid; idx < 8*16; idx += 256){
    int ml = idx>>4, g = idx&15;
    #pragma unroll
    for(int k=16;k<32;k++) w2kT[ml][g][k] = 0;
  }
  for(int sb = 0; sb < 4; sb++){                  // grid 2048 x 4 slices x 8 = M
    const int base = (blockIdx.x*4 + sb)*8;
    if(tid < 8) mm[tid] = perm[base + tid];
    __syncthreads();
    if(tid < 128){ int ml = tid>>4, k = tid&15; refs[ml][k] = ri[(size_t)clu[mm[ml]]*16 + k]; }
    else if(tid < 160){ int q = tid-128; int ml = q>>2, d = q&3; if(d<3) scm[ml][d] = skc[(size_t)mm[ml]*3 + d]; }
    else if(tid < 168){ int q = tid-160;
      int n = clu[mm[q]];
      int ld = q;
      for(int j=0;j<q;j++) if(clu[mm[j]] == n){ ld = j; break; }
      leader[q] = ld; }
    // fused F1 stage A: ul[ml][k][j] = relu(bn2(w1[m][k*16+j])) into hkc region
    {
      float* ulp = (float*)&hkc[0][0][0];     // ul(ml,k,j) = ulp[ml*272 + k*17 + j]
      const int mlu = tid >> 5, ju = tid & 15, khu = (tid >> 4) & 1;
      const u16* wrow = w1 + (size_t)mm[mlu]*256 + khu*128 + ju;
      #pragma unroll
      for(int i=0;i<8;i++){
        int k = khu*8 + i;
        float v = uf(wrow[i*16]);
        ulp[mlu*272 + k*17 + ju] = fmaxf(s2j*v + t2j, 0.f);
      }
    }
    __syncthreads();
    // fused F1 stage B: w2 + softmax -> w2kT[ml][j][k]; bs2F (independent)
    if(tid < 128){
      const int mlw = tid >> 4, jw = tid & 15;
      const float* ulp = (const float*)&hkc[0][0][0];
      float w2v[16];
      float mx = -1e30f;
      #pragma unroll
      for(int k=0;k<16;k++){
        float a = bw2j;
        #pragma unroll
        for(int g=0; g<16; g++) a += ulp[mlw*272 + k*17 + g]*ww2c[g];
        w2v[k] = a; mx = fmaxf(mx, a);
      }
      float den = 0.f;
      #pragma unroll
      for(int k=0;k<16;k++){ w2v[k] = __expf(w2v[k]-mx); den += w2v[k]; }
      float inv = 1.f/den;
      #pragma unroll
      for(int k=0;k<16;k++) w2kT[mlw][jw][k] = fu(w2v[k]*inv);
    }
    #pragma unroll
    for(int ml=0; ml<8; ml++)
      bs2F[ml][tid] = s1c*(scm[ml][0]*w0 + scm[ml][1]*w1g + scm[ml][2]*w2g);
    f32x4 accG[4];
    #pragma unroll
    for(int gi=0; gi<4; gi++) accG[gi] = (f32x4){0.f,0.f,0.f,0.f};
    __syncthreads();
    for(int q=0; q<8; q++){
      // phase1: wave wv gathers h for ml = 2wv..2wv+1 into hkc (intra-wave with phase3)
      {
        const int cl = tid & 31, mlh = tid >> 5;
        const int cg = q*32 + cl;
        const float bsv = bs2F[mlh][cg];
        union { i32x4 v[2]; u16 a[16]; } hr;
        #pragma unroll
        for(int k=0;k<16;k++){
          float a = uf(As[(size_t)refs[mlh][k]*256 + cg]);
          hr.a[k] = fu(fmaxf(a - bsv, 0.f));
        }
        *(i32x4*)(&hkc[mlh][cl][0])  = hr.v[0];
        *(i32x4*)(&hkc[mlh][cl][8])  = hr.v[1];
        *(i32x4*)(&hkc[mlh][cl][16]) = (i32x4){0,0,0,0};
        *(i32x4*)(&hkc[mlh][cl][24]) = (i32x4){0,0,0,0};
      }
      // NO barrier: phase3 wave wv reads exactly hkc[2wv..2wv+1] it just wrote
      #pragma unroll
      for(int mq=0; mq<2; mq++){
        const int ml = wv*2 + mq;
        #pragma unroll
        for(int ct=0; ct<2; ct++){
          s16x8 af = *(const s16x8*)(&w2kT[ml][lane & 15][(lane>>4)*8]);
          s16x8 bf = *(const s16x8*)(&hkc[ml][ct*16 + (lane & 15)][(lane>>4)*8]);
          f32x4 d = __builtin_amdgcn_mfma_f32_16x16x32_bf16(af, bf, (f32x4){0.f,0.f,0.f,0.f}, 0,0,0);
          #pragma unroll
          for(int r=0;r<4;r++){
            int g = (lane>>4)*4 + r;
            Tb[ml][g][ct*16 + (lane & 15)] = fu(d[r]);
          }
        }
      }
      __syncthreads();
      // phase4 (MFMA): accG += T @ W2T  (Tb cross-wave)
      #pragma unroll
      for(int gi=0; gi<4; gi++){
        const int g = wv*4 + gi;
        s16x8 tf = (s16x8){0,0,0,0,0,0,0,0};
        if((lane & 15) < 8)
          tf = *(const s16x8*)(&Tb[lane & 15][g][(lane>>4)*8]);
        s16x8 pf = *(const s16x8*)(&W2T[(size_t)(g*16 + (lane & 15))*256 + q*32 + (lane>>4)*8]);
        accG[gi] = __builtin_amdgcn_mfma_f32_16x16x32_bf16(tf, pf, accG[gi], 0,0,0);
      }
      __syncthreads();
    }
    float* opeb = (float*)&Tb[0][0][0];
    #pragma unroll
    for(int gi=0; gi<4; gi++){
      const int g = wv*4 + gi;
      #pragma unroll
      for(int r=0;r<4;r++){
        int ml = (lane>>4)*4 + r;
        if(ml < 8) opeb[ml*260 + g*16 + (lane & 15)] = accG[gi][r];
      }
    }
    __syncthreads();
    // phase5: leader-dedup lres gathers
    {
      const int cc = tid, g = cc>>4;
      const float bp2c = bp2[cc];
      u16 lv[16];
      #pragma unroll
      for(int ml=0; ml<8; ml++){
        if(leader[ml] == ml){
          #pragma unroll
          for(int k=0;k<16;k++) lv[k] = lres[(size_t)refs[ml][k]*256 + cc];
        }
        union { s16x8 v; u16 a[8]; } wr0, wr1;
        wr0.v = *(const s16x8*)(&w2kT[ml][g][0]);
        wr1.v = *(const s16x8*)(&w2kT[ml][g][8]);
        float ol0 = 0.f, ol1 = 0.f;
        #pragma unroll
        for(int k=0;k<8;k++){
          ol0 += uf(wr0.a[k])*uf(lv[k]);
          ol1 += uf(wr1.a[k])*uf(lv[k+8]);
        }
        size_t m = (size_t)mm[ml];
        outp[m*256 + cc] = opeb[ml*260 + cc] + bp2c + (ol0 + ol1) + uf(skipP[m*256 + cc]);
      }
    }
    __syncthreads();
  }
}

// ---------------------------------------------------------------------------
extern "C" void kernel_launch(void* const* d_in, const int* in_sizes, int n_in,
                              void* d_out, int out_size, void* d_ws, size_t ws_size,
                              hipStream_t stream){
  (void)in_sizes; (void)n_in;
  const float *coord=(const float*)d_in[0], *feat=(const float*)d_in[1];
  const float *skc=(const float*)d_in[2],   *skf=(const float*)d_in[3];
  const int *clu=(const int*)d_in[4],   *ri=(const int*)d_in[5];
  const float *Wp=(const float*)d_in[6],  *bp=(const float*)d_in[7],  *gp=(const float*)d_in[8],  *bep=(const float*)d_in[9];
  const float *Wsk=(const float*)d_in[10],*bs=(const float*)d_in[11], *gs=(const float*)d_in[12], *bes=(const float*)d_in[13];
  const float *Wk=(const float*)d_in[14], *bk=(const float*)d_in[15], *gk=(const float*)d_in[16], *bek=(const float*)d_in[17];
  const float *Wq=(const float*)d_in[18], *bq=(const float*)d_in[19], *gq=(const float*)d_in[20], *beq=(const float*)d_in[21];
  const float *Wp1=(const float*)d_in[22],                           *gp1=(const float*)d_in[24], *bep1=(const float*)d_in[25];
  const float *Wp2=(const float*)d_in[26], *bp2=(const float*)d_in[27];
  const float *Ww1=(const float*)d_in[28], *bw1=(const float*)d_in[29], *gw1=(const float*)d_in[30], *bew1=(const float*)d_in[31];
  const float *Ww2=(const float*)d_in[32], *bw2=(const float*)d_in[33];

  constexpr size_t OFF_A    = 0;          // bf16 [N,256]  A -> As (in-place)
  constexpr size_t OFF_LRES = 8388608;    // bf16 [N,256]
  constexpr size_t OFF_NY   = 16777216;   // bf16 [N,256]  Yp->Yk, then sort scratch
  constexpr size_t OFF_SKP  = 25165824;   // bf16 [M,256]
  constexpr size_t OFF_M1   = 58720256;   // bf16 [M,256]  Ys->Yq->w1raw
  constexpr size_t OFF_M2   = 92274688;   // bf16 [M,256]  hres
  constexpr size_t OFF_KW   = 125829120;  // f32 [N,16]
  constexpr size_t OFF_QW   = 126877696;  // f32 [M,16]
  constexpr size_t OFF_ACC  = 131072000;  // f32 accumulators (zeroed)
  constexpr size_t OFF_PAR  = 131084288;  // f32 params (+ bf16 W21T)
  constexpr size_t OFF_W2T  = 131117056;  // bf16 [256][256] Wp2 transposed
  constexpr size_t NEED     = 131248128;

  if(ws_size < NEED){
    k_fill<<<65536, 256, 0, stream>>>((float*)d_out, out_size);
    return;
  }
  char* ws = (char*)d_ws;
  u16* Ab    = (u16*)(ws + OFF_A);
  u16* lresb = (u16*)(ws + OFF_LRES);
  u16* nY    = (u16*)(ws + OFF_NY);
  u16* skipP = (u16*)(ws + OFF_SKP);
  u16* M1    = (u16*)(ws + OFF_M1);
  u16* M2    = (u16*)(ws + OFF_M2);
  float* KWp = (float*)(ws + OFF_KW);
  float* QWp = (float*)(ws + OFF_QW);
  u16* W2Tp  = (u16*)(ws + OFF_W2T);
  int* cntp  = (int*)(ws + OFF_NY);             // 16384 i32 (also cursor)
  int* offsp = (int*)(ws + OFF_NY + 65536);     // 16384 i32
  int* permp = (int*)(ws + OFF_NY + 131072);    // 65536 i32
  float* ACC = (float*)(ws + OFF_ACC);
  float *gs0 = ACC+0,    *gq0 = ACC+256;
  float *gs1 = ACC+512,  *gq1 = ACC+768;
  float *gs2 = ACC+1024, *gq2 = ACC+1280;
  float *gs3 = ACC+1536, *gq3 = ACC+1792;
  float *b1s = ACC+2048, *b1q = ACC+2304;
  float *b2s = ACC+2560; // b2q = b2s+16
  float* PAR = (float*)(ws + OFF_PAR);
  float *sB0 = PAR+0,    *tB0 = PAR+256;
  float *sB1 = PAR+512,  *tB1 = PAR+768;
  float *sB2 = PAR+1024, *tB2 = PAR+1280;
  float *sB3 = PAR+1536, *tB3 = PAR+1792;
  float *s1p = PAR+2048, *t1p = PAR+2304;
  float *s2p = PAR+2560, *t2p = PAR+2576;
  float *c0p = PAR+2592;
  u16  *W21Tp= (u16*)(PAR+2608);  // bf16 [16][256] = 8 KB

  hipMemsetAsync(ws + OFF_ACC, 0, 12288, stream);

  k_prep<<<256, 256, 0, stream>>>(Wp2, Ww1, bw1, bp2, W21Tp, c0p, W2Tp);
  k_A<<<16384, 256, 0, stream>>>(coord, Wp1, Ab);

  // proj: Yp = feat@Wp + bp  -> lres   (stats fused in gemm)
  k_gemm<float,256><<<dim3(256,4), 256, 0, stream>>>(feat, Wp, bp, nY, gs0, gq0);
  k_fin<<<1, 256, 0, stream>>>(gs0, gq0, gp, bep, 1.f/(float)NN, 256, sB0, tB0);
  k_lres<<<2048, 256, 0, stream>>>(nY, sB0, tB0, lresb);

  // proj_skip: Ys = skf@Ws + bs -> skipP, hres
  k_gemm<float,128><<<dim3(1024,4), 256, 0, stream>>>(skf, Wsk, bs, M1, gs1, gq1);
  k_fin<<<1, 256, 0, stream>>>(gs1, gq1, gs, bes, 1.f/(float)MM, 256, sB1, tB1);
  k_hres<<<8192, 256, 0, stream>>>(M1, sB1, tB1, lresb, clu, skipP, M2);

  // key: Yk = lres@Wk + bk; KW = relu(bn(Yk))@Ww1  (MFMA proj16)
  k_gemm<u16,256><<<dim3(256,4), 256, 0, stream>>>(lresb, Wk, bk, nY, gs2, gq2);
  k_fin<<<1, 256, 0, stream>>>(gs2, gq2, gk, bek, 1.f/(float)NN, 256, sB2, tB2);
  k_proj16m<<<256, 256, 0, stream>>>(nY, sB2, tB2, Ww1, KWp);   // last nY use

  // counting sort of m by cluster
  hipMemsetAsync(cntp, 0, 65536, stream);
  k_count<<<256, 256, 0, stream>>>(clu, cntp);
  k_scan<<<1, 256, 0, stream>>>(cntp, offsp);
  k_scatter<<<256, 256, 0, stream>>>(clu, offsp, cntp, permp);

  // query: Yq = hres@Wq + bq; QW = relu(bn(Yq))@Ww1  (MFMA proj16)
  k_gemm<u16,256><<<dim3(1024,4), 256, 0, stream>>>(M2, Wq, bq, M1, gs3, gq3);
  k_fin<<<1, 256, 0, stream>>>(gs3, gq3, gq, beq, 1.f/(float)MM, 256, sB3, tB3);
  k_proj16m<<<1024, 256, 0, stream>>>(M1, sB3, tB3, Ww1, QWp);

  // BN1 (cluster-dedup stats on raw A), then fold affine into A (A -> As)
  k_bn1stats<<<1024, 256, 0, stream>>>(Ab, ri, clu, skc, Wp1, permp, b1s, b1q);
  k_fin<<<1, 256, 0, stream>>>(b1s, b1q, gp1, bep1, 1.f/(float)MKCNT, 256, s1p, t1p);
  k_Astar<<<2048, 256, 0, stream>>>(Ab, s1p, t1p);

  // w1raw (MFMA S2 + fused BN2 stats, intra-wave phase1->phase2)
  k_S2h<<<2048, 256, 0, stream>>>(Ab, ri, clu, skc, Wp1, s1p, KWp, QWp, W21Tp, c0p, permp, M1, b2s);
  k_fin<<<1, 256, 0, stream>>>(b2s, b2s+16, gw1, bew1, 1.f/(float)MKCNT, 16, s2p, t2p);

  // final output (F1 fused; intra-wave phase1->phase3)
  k_F2t<<<2048, 256, 0, stream>>>(Ab, ri, clu, skc, Wp1, s1p, M1, W2Tp, bp2, lresb, skipP, permp,
                                  s2p, t2p, Ww2, bw2, (float*)d_out);
}